// Round 6
// baseline (269.347 us; speedup 1.0000x reference)
//
#include <hip/hip_runtime.h>
#include <hip/hip_bf16.h>

// ---------------------------------------------------------------------------
// DRSAR_FL_RNN: B=512, T=128, F=256, H=512, K=3
// R13 = R12 with the accq spread (8 ds_bpermute + 8 cndmask per wave-step)
// replaced by a per-wave LDS exchange integrated into the pair structure:
//   - after pair-A chains: lanes 0-15 (C rows 0,1 = quad0 regs 0,1) export
//     {acc[nt][0],acc[nt][1]} as masked-16 ds_write_b64, stride 8B
//     (conflict-free, ~2 cyc) -- hidden under pair-B's 16 MFMAs.
//   - after pair-B export: one lgkmcnt(0) + ONE 64-lane ds_read_b64 gives
//     each lane {accq[0],accq[1]} directly (512B = LDS BW floor, ~6 cyc).
//   - kills 8 bpermutes (~40 cyc LDS busy/wave) + 8 cndmask selects.
// LDS-pipe busy per CU-step drops ~320 -> ~90 cyc for the spread phase.
// Everything else identical to R12 (raw lgkm-only barrier, nt-pair chains,
// fma-form Gaussian, v_perm qb pack, fused prep, 2-row h mirror).
// ---------------------------------------------------------------------------

#define B_  512
#define T_  128
#define F_  256
#define H_  512
#define LOG2E 1.4426950408889634f

// xw2 per-timestep stride in ushorts: [256 bg][8 w][64 lane][2 el]
#define XW_T_STRIDE 262144

typedef __attribute__((ext_vector_type(8))) short short8;
typedef __attribute__((ext_vector_type(4))) float float4v;
typedef __attribute__((ext_vector_type(4))) int int4i;
typedef __attribute__((ext_vector_type(2))) int int2v;

__device__ inline ushort f2bf(float f) {
  __hip_bfloat16 h = __float2bfloat16(f);
  return *reinterpret_cast<ushort*>(&h);
}
__device__ inline float bf2f(unsigned u) { return __uint_as_float(u << 16); }
__device__ inline float fexp2(float x) { return __builtin_amdgcn_exp2f(x); }
__device__ inline float frcp(float x) { return __builtin_amdgcn_rcpf(x); }

// ws layout (bytes):
//   xw2  bf16 [T][256 bg][8 w][64 lane][2 el]          : 0 .. 67108864
//   W2I8 i8 frag-linear [8 kt][32 nb][64 lane][16 B]   : 67108864 (262144)
//   WXF  bf16 frag-linear [8 kt][32 nb][64 lane][8]    : 67371008 (262144)
//   GP8  f32 [512][8]                                  : 67633152 (16384)
//   BVEC f32 [512]                                     : 67649536
//   WCV  f32 [512]                                     : 67651584
//   SCOL f32 [512]                                     : 67653632
//   WTS  f32 [256]                                     : 67657728
#define WS_W2I8 67108864
#define WS_WXF  67371008
#define WS_GP8  67633152
#define WS_BVEC 67649536
#define WS_WCV  67651584
#define WS_SCOL 67653632
#define WS_WTS  67657728

// blocks 0-31: Wh column-scales + i8 quant (frag-linear W2), coalesced reads.
// blocks 32-39: Wx -> WxF bf16 frag-linear via LDS transpose.
// block 40: tiny per-element prep: weights=sigmoid(theta), gating consts, b, Wc.
__global__ __launch_bounds__(256) void prep_weights(
    const float* __restrict__ Wh, const float* __restrict__ Wx,
    const float* __restrict__ theta, const float* __restrict__ b,
    const float* __restrict__ c, const float* __restrict__ sigma,
    const float* __restrict__ q, const float* __restrict__ Wc,
    int* __restrict__ W2, ushort* __restrict__ WxF,
    float* __restrict__ scol, float* __restrict__ out_w,
    float* __restrict__ gp8, float* __restrict__ bvec,
    float* __restrict__ wcv, float* __restrict__ wts) {
  __shared__ float lds[16544];  // 66176 B; reused by both roles
  const int t = threadIdx.x;

  if (blockIdx.x < 32) {
    const int nb = blockIdx.x;
    // phase 1: column absmax over 16 cols, coalesced 64B runs
    const int cc = t & 15, rg = t >> 4;
    float m = 0.f;
#pragma unroll
    for (int s = 0; s < 32; ++s)
      m = fmaxf(m, fabsf(Wh[(rg + s * 16) * H_ + nb * 16 + cc]));
    lds[rg * 16 + cc] = m;
    __syncthreads();
    if (t < 16) {
      float mm = lds[t];
#pragma unroll
      for (int s = 1; s < 16; ++s) mm = fmaxf(mm, lds[s * 16 + t]);
      mm = fmaxf(mm, 1e-20f);
      scol[nb * 16 + t] = mm / (127.f * 127.f);
      lds[256 + t] = 127.f / mm;
    }
    __syncthreads();
    // phase 2: quantize, W2 layout identical to R7
    const int lane = t & 63, dw = t >> 6;
    const int n = nb * 16 + (lane & 15);
    const float iv = lds[256 + (lane & 15)];
#pragma unroll
    for (int kt = 0; kt < 8; ++kt) {
      int pk = 0;
#pragma unroll
      for (int jj = 0; jj < 4; ++jj) {
        const int k = kt * 64 + ((lane >> 4) << 4) + dw * 4 + jj;
        int qv = (int)rintf(Wh[k * H_ + n] * iv);
        qv = min(127, max(-127, qv));
        pk |= (qv & 255) << (8 * jj);
      }
      W2[((kt * 32 + nb) * 64 + lane) * 4 + dw] = pk;
    }
  } else if (blockIdx.x < 40) {
    const int kt = blockIdx.x - 32;
    // stage Wx rows [kt*32, kt*32+32) x 512 into LDS, row stride 517
#pragma unroll
    for (int it = 0; it < 16; ++it) {
      const int lin = (it * 256 + t) * 4;
      const float4 v = *(const float4*)(Wx + kt * 32 * H_ + lin);
      const int f = lin >> 9, n0 = lin & 511;
      lds[f * 517 + n0 + 0] = v.x;
      lds[f * 517 + n0 + 1] = v.y;
      lds[f * 517 + n0 + 2] = v.z;
      lds[f * 517 + n0 + 3] = v.w;
    }
    __syncthreads();
    // write frag-linear: o = (nb*64+lane)*8 + j, coalesced 16B/lane runs
#pragma unroll
    for (int it = 0; it < 8; ++it) {
      const int o = (it * 256 + t) * 8;
      const int lane = (o >> 3) & 63, nb = o >> 9;
      const int n = nb * 16 + (lane & 15), fb = (lane >> 4) << 3;
      ushort v[8];
#pragma unroll
      for (int j = 0; j < 8; ++j) v[j] = f2bf(lds[(fb + j) * 517 + n]);
      *(short8*)(WxF + kt * 16384 + o) = *(short8*)v;
    }
  } else {
    // ex prep_small: 256 threads handle 512 items (i = t, t+256)
#pragma unroll
    for (int r = 0; r < 2; ++r) {
      const int i = t + r * 256;
      if (i < F_) {
        float w = 1.f / (1.f + __expf(-theta[i]));
        out_w[i] = w;
        wts[i] = w;
      }
      float a[3], cc[3], qq[3];
#pragma unroll
      for (int k = 0; k < 3; ++k) {
        float s = sigma[i * 3 + k];
        cc[k] = c[i * 3 + k];
        a[k] = -LOG2E / (2.f * s * s + 1e-8f);
        qq[k] = q[i * 3 + k];
      }
      gp8[i * 8 + 0] = cc[0];
      gp8[i * 8 + 1] = cc[1];
      gp8[i * 8 + 2] = cc[2];
      gp8[i * 8 + 3] = a[0];
      gp8[i * 8 + 4] = a[1];
      gp8[i * 8 + 5] = a[2];
      gp8[i * 8 + 6] = __uint_as_float((unsigned)f2bf(qq[0]) |
                                       ((unsigned)f2bf(qq[1]) << 16));
      gp8[i * 8 + 7] = __uint_as_float((unsigned)f2bf(qq[2]));
      bvec[i] = b[i];
      wcv[i] = Wc[i];
    }
  }
}

// xw2 = bf16(x*wts) @ bf16(Wx), stored in scan4's layout.
// grid (t=128, bblk64=8), 256 thr. Batched B-frag loads (16 in flight).
__global__ __launch_bounds__(256, 1) void gemm1_kernel(
    const float* __restrict__ x, const float* __restrict__ wts,
    const ushort* __restrict__ WxF, ushort* __restrict__ xw2) {
  __shared__ ushort A[64 * 264];
  const int tid = threadIdx.x;
  const int lane = tid & 63, wg = tid >> 6;
  const int col16 = lane & 15, quad = lane >> 4;
  const int tt = blockIdx.x, bb = blockIdx.y;

  {  // stage A coalesced: wave reads one contiguous 1KB row per iteration
    const float4 wv = *(const float4*)(wts + lane * 4);
#pragma unroll
    for (int it = 0; it < 16; ++it) {
      const int row = it * 4 + wg;
      float4 xv = *(const float4*)(x + ((size_t)(bb * 64 + row) * T_ + tt) * F_ + lane * 4);
      ushort4 o;
      o.x = f2bf(xv.x * wv.x);
      o.y = f2bf(xv.y * wv.y);
      o.z = f2bf(xv.z * wv.z);
      o.w = f2bf(xv.w * wv.w);
      *(ushort4*)&A[row * 264 + lane * 4] = o;
    }
  }
  __syncthreads();

  const float4v zero = {0.f, 0.f, 0.f, 0.f};
#pragma unroll
  for (int nn = 0; nn < 2; ++nn) {
    float4v acc[16];
#pragma unroll
    for (int i = 0; i < 16; ++i) acc[i] = zero;
#pragma unroll
    for (int kt = 0; kt < 8; ++kt) {
      short8 af = *(const short8*)&A[(wg * 16 + col16) * 264 + kt * 32 + quad * 8];
      short8 bfv[16];
#pragma unroll
      for (int nt = 0; nt < 16; ++nt)
        bfv[nt] = *(const short8*)(WxF + ((kt * 32 + nn * 16 + nt) * 64 + lane) * 8);
#pragma unroll
      for (int nt = 0; nt < 16; ++nt)
        acc[nt] = __builtin_amdgcn_mfma_f32_16x16x32_bf16(af, bfv[nt], acc[nt], 0, 0, 0);
    }
    // store into scan4 layout (unchanged from R7)
#pragma unroll
    for (int nt = 0; nt < 16; ++nt) {
      ushort2 lo, hi;
      lo.x = f2bf(acc[nt][0]);
      lo.y = f2bf(acc[nt][1]);
      hi.x = f2bf(acc[nt][2]);
      hi.y = f2bf(acc[nt][3]);
      const int bg0 = bb * 32 + wg * 8 + quad * 2;
      const size_t off0 =
          (((size_t)tt * 256 + bg0) * 8 + nn * 4 + (nt >> 2)) * 128 +
          ((nt & 3) * 16 + col16) * 2;
      *(ushort2*)(xw2 + off0) = lo;
      *(ushort2*)(xw2 + off0 + 1024) = hi;  // bg0+1
    }
  }
}

// scan4: 256 WGs x 512 thr (8 waves); WG owns 2 batch rows; wave owns 64
// cols. h mirror: 2-row i8 LDS buffer (double-buffered, row stride 576);
// only lanes col16<2 read A-frags (8 ds_read_b128/wave, conflict-free).
// MFMA as two nt-pair chains; per-wave LDS exchange for the C-row spread.
// Raw barrier (lgkmcnt-only) keeps the xn prefetch in flight across steps.
__global__ __launch_bounds__(512, 2) void scan4_kernel(
    const ushort* __restrict__ xw2, const int4i* __restrict__ W2,
    const float* __restrict__ gp8, const float* __restrict__ bvec,
    const float* __restrict__ wcv, const float* __restrict__ scol,
    const float* __restrict__ bc, float* __restrict__ out) {
  __shared__ __align__(16) char hb[2][1152];  // [buf][row*576 + k], rows 0..1
  __shared__ __align__(16) int exch[8][4][16][2];  // [w][nt][c][rg], 4 KB
  __shared__ float red[8][2];
  const int tid = threadIdx.x;
  const int lane = tid & 63, w = tid >> 6;
  const int col16 = lane & 15, quad = lane >> 4;
  const int bg = blockIdx.x;

  for (int i = tid; i < 576; i += 512) ((int*)hb)[i] = 0;

  int4i bfr[8][4];
#pragma unroll
  for (int kt = 0; kt < 8; ++kt)
#pragma unroll
    for (int nt = 0; nt < 4; ++nt)
      bfr[kt][nt] = W2[(kt * 32 + w * 4 + nt) * 64 + lane];

  const int col = w * 64 + lane;
  const float bcol = bvec[col], scl = scol[col], wcl = wcv[col];
  float4v g0 = *(const float4v*)(gp8 + col * 8);
  float4v g1 = *(const float4v*)(gp8 + col * 8 + 4);
  const float c0v = g0[0], c1v = g0[1], c2v = g0[2];
  const float a0v = g0[3], a1v = g1[0], a2v = g1[1];
  unsigned p01 = __float_as_uint(g1[2]);
  const float q0v = bf2f(p01 & 0xffffu);
  const float q1v = bf2f(p01 >> 16);
  const float q2v = bf2f(__float_as_uint(g1[3]) & 0xffffu);
  // fma-form Gaussian: m = exp2(a*z^2 + b*z + d), b=-2ac, d=a*c^2
  const float b0v = -2.f * a0v * c0v, d0v = a0v * c0v * c0v;
  const float b1v = -2.f * a1v * c1v, d1v = a1v * c1v * c1v;
  const float b2v = -2.f * a2v * c2v, d2v = a2v * c2v * c2v;

  // write-back pack: even lane stores row0 (cols c,c+1), odd lane row1
  // (cols c-1,c). v_perm sel: 0-3 pick bytes of src1(p1), 4-7 of src0(pk).
  const unsigned wsel = (lane & 1) ? 0x0501u : 0x0004u;
  const int woff = col + ((lane & 1) ? 575 : 0);

  // per-wave exchange pointers
  int* const exb = &exch[w][0][0][0];
  int* const exw = exb + lane * 2;           // write slot for lanes 0-15 (c)
  const int* const exr = exb + (quad * 16 + col16) * 2;  // read slot

  float hreg[2] = {0.f, 0.f};
  const int4i izero = {0, 0, 0, 0};
  int4i areg[8];
#pragma unroll
  for (int kt = 0; kt < 8; ++kt) areg[kt] = izero;  // lanes col16>=2 stay 0

  const ushort* xwb = xw2 + ((size_t)bg * 8 + w) * 128 + lane * 2;
  unsigned xv = *(const unsigned*)xwb;
  unsigned xn;
  __syncthreads();

#pragma clang loop unroll(disable)
  for (int t = 0; t < T_; ++t) {
    const int tn = (t + 1) & 127;
    xn = *(const unsigned*)(xwb + (size_t)tn * XW_T_STRIDE);

    if (col16 < 2) {
      const char* abase = hb[t & 1] + col16 * 576;
#pragma unroll
      for (int kt = 0; kt < 8; ++kt)
        areg[kt] = *(const int4i*)(abase + kt * 64 + (quad << 4));
    }

    // pair A: nt 0,1 chains
    int4i acc0 = izero, acc1 = izero;
#pragma unroll
    for (int kt = 0; kt < 8; ++kt) {
      acc0 = __builtin_amdgcn_mfma_i32_16x16x64_i8(areg[kt], bfr[kt][0], acc0, 0, 0, 0);
      acc1 = __builtin_amdgcn_mfma_i32_16x16x64_i8(areg[kt], bfr[kt][1], acc1, 0, 0, 0);
    }
    // export pair A (C rows 0,1 live in quad0 = lanes 0-15, regs 0,1);
    // masked-16 b64 writes, hidden under pair-B's MFMAs
    if (lane < 16) {
      int2v e0, e1;
      e0[0] = acc0[0]; e0[1] = acc0[1];
      e1[0] = acc1[0]; e1[1] = acc1[1];
      *(int2v*)exw = e0;           // [0][c][*]
      *(int2v*)(exw + 32) = e1;    // [1][c][*]
    }
    // pair B: nt 2,3 chains
    int4i acc2 = izero, acc3 = izero;
#pragma unroll
    for (int kt = 0; kt < 8; ++kt) {
      acc2 = __builtin_amdgcn_mfma_i32_16x16x64_i8(areg[kt], bfr[kt][2], acc2, 0, 0, 0);
      acc3 = __builtin_amdgcn_mfma_i32_16x16x64_i8(areg[kt], bfr[kt][3], acc3, 0, 0, 0);
    }
    if (lane < 16) {
      int2v e2, e3;
      e2[0] = acc2[0]; e2[1] = acc2[1];
      e3[0] = acc3[0]; e3[1] = acc3[1];
      *(int2v*)(exw + 64) = e2;    // [2][c][*]
      *(int2v*)(exw + 96) = e3;    // [3][c][*]
    }
    asm volatile("s_waitcnt lgkmcnt(0)" ::: "memory");
    // one b64 read: {accq[0], accq[1]} for this lane's column
    int2v aq = *(const int2v*)exr;
    int accq[2];
    accq[0] = aq[0];
    accq[1] = aq[1];

    int qb[2];
#pragma unroll
    for (int rg = 0; rg < 2; ++rg) {
      float v = __uint_as_float(rg ? (xv & 0xffff0000u) : (xv << 16));
      float z = v + bcol + (float)accq[rg] * scl;
      float e = fexp2(v * (2.f * LOG2E));
      float nw = 1.f - 2.f * frcp(1.f + e);            // tanh(v)
      float zz = z * z;
      float m0 = fexp2(fmaf(a0v, zz, fmaf(b0v, z, d0v)));
      float m1 = fexp2(fmaf(a1v, zz, fmaf(b1v, z, d1v)));
      float m2 = fexp2(fmaf(a2v, zz, fmaf(b2v, z, d2v)));
      float num = m0 * q0v + m1 * q1v + m2 * q2v;
      float den = m0 + m1 + m2 + 1e-8f;
      float s = num * frcp(den);
      float gg = frcp(1.f + fexp2(-s * LOG2E));        // sigmoid(s)
      float h = hreg[rg] + gg * (nw - hreg[rg]);
      hreg[rg] = h;
      qb[rg] = (int)rintf(h * 127.f);
    }

    if (t < T_ - 1) {
      // pk byte0 = qb0.b0, byte1 = qb1.b0
      int pk = (int)__builtin_amdgcn_perm((unsigned)qb[1], (unsigned)qb[0], 0x0400u);
      unsigned p1 = (unsigned)__shfl_xor(pk, 1, 64);
      unsigned v16 = __builtin_amdgcn_perm((unsigned)pk, p1, wsel);
      *(ushort*)(hb[(t + 1) & 1] + woff) = (ushort)v16;
      // raw barrier: flush LDS ops only; keep xn global prefetch in flight
      asm volatile("s_waitcnt lgkmcnt(0)" ::: "memory");
      __builtin_amdgcn_s_barrier();
      __builtin_amdgcn_sched_barrier(0);  // keep A-reads below the barrier
    }
    xv = xn;
  }

  float part[2];
#pragma unroll
  for (int rg = 0; rg < 2; ++rg) {
    part[rg] = hreg[rg] * wcl;
#pragma unroll
    for (int m = 1; m < 64; m <<= 1) part[rg] += __shfl_xor(part[rg], m, 64);
  }
  if (lane == 0) {
    red[w][0] = part[0];
    red[w][1] = part[1];
  }
  __syncthreads();
  if (tid < 2) {
    float s = bc[0];
#pragma unroll
    for (int ww = 0; ww < 8; ++ww) s += red[ww][tid];
    out[bg * 2 + tid] = s;
  }
}

extern "C" void kernel_launch(void* const* d_in, const int* in_sizes, int n_in,
                              void* d_out, int out_size, void* d_ws, size_t ws_size,
                              hipStream_t stream) {
  const float* x     = (const float*)d_in[0];
  const float* theta = (const float*)d_in[1];
  const float* Wx    = (const float*)d_in[2];
  const float* Wh    = (const float*)d_in[3];
  const float* b     = (const float*)d_in[4];
  const float* c     = (const float*)d_in[5];
  const float* sigma = (const float*)d_in[6];
  const float* q     = (const float*)d_in[7];
  const float* Wc    = (const float*)d_in[8];
  const float* bc    = (const float*)d_in[9];
  float* out = (float*)d_out;

  ushort* xw2 = (ushort*)d_ws;
  int*    W2  = (int*)((char*)d_ws + WS_W2I8);
  ushort* WxF = (ushort*)((char*)d_ws + WS_WXF);
  float*  gp8 = (float*)((char*)d_ws + WS_GP8);
  float*  bv  = (float*)((char*)d_ws + WS_BVEC);
  float*  wcv = (float*)((char*)d_ws + WS_WCV);
  float*  scl = (float*)((char*)d_ws + WS_SCOL);
  float*  wts = (float*)((char*)d_ws + WS_WTS);

  hipLaunchKernelGGL(prep_weights, dim3(41), dim3(256), 0, stream,
                     Wh, Wx, theta, b, c, sigma, q, Wc,
                     W2, WxF, scl, out + B_, gp8, bv, wcv, wts);
  hipLaunchKernelGGL(gemm1_kernel, dim3(128, 8), dim3(256), 0, stream,
                     x, wts, WxF, xw2);
  hipLaunchKernelGGL(scan4_kernel, dim3(256), dim3(512), 0, stream,
                     xw2, (const int4i*)W2, gp8, bv, wcv, scl, bc, out);
}

// Round 7
// 250.463 us; speedup vs baseline: 1.0754x; 1.0754x over previous
//
#include <hip/hip_runtime.h>
#include <hip/hip_bf16.h>

// ---------------------------------------------------------------------------
// DRSAR_FL_RNN: B=512, T=128, F=256, H=512, K=3
// R14 = scan4 reverted to R11 (best measured: 133.0us) + gemm1 rebuilt with
// 2-timestep blocking:
//   - grid (64,8): block computes t in {tt2, tt2+64} for its 64 rows.
//   - A-tile 2 x [64][256] ushort (64KB exactly), XOR-swizzled 16B units
//     (chunk ^= row&7) -> af column-reads 2-way bank = free, no pad.
//   - each bfv global load now feeds 2 MFMAs (acc0/acc1) -> B-side L1/L2
//     traffic halves (was: every wave streams all 256KB of WxF per block
//     with zero reuse).
//   - __launch_bounds__(256,2): VGPR cap 256 (acc 128 + bfv 64) so the 512
//     blocks stay 2/CU co-resident.
// prep_weights unchanged from R13 (fused 41-block prep).
// Scan rounds R12/R13 (raw barrier, LDS exchange) were neutral: the scan
// tail is a latency-bound serial chain, not issue-bound -> structural floor
// for this decomposition; stop polishing it.
// ---------------------------------------------------------------------------

#define B_  512
#define T_  128
#define F_  256
#define H_  512
#define LOG2E 1.4426950408889634f

// xw2 per-timestep stride in ushorts: [256 bg][8 w][64 lane][2 el]
#define XW_T_STRIDE 262144

typedef __attribute__((ext_vector_type(8))) short short8;
typedef __attribute__((ext_vector_type(4))) float float4v;
typedef __attribute__((ext_vector_type(4))) int int4i;

__device__ inline ushort f2bf(float f) {
  __hip_bfloat16 h = __float2bfloat16(f);
  return *reinterpret_cast<ushort*>(&h);
}
__device__ inline float bf2f(unsigned u) { return __uint_as_float(u << 16); }
__device__ inline float fexp2(float x) { return __builtin_amdgcn_exp2f(x); }
__device__ inline float frcp(float x) { return __builtin_amdgcn_rcpf(x); }

// ws layout (bytes):
//   xw2  bf16 [T][256 bg][8 w][64 lane][2 el]          : 0 .. 67108864
//   W2I8 i8 frag-linear [8 kt][32 nb][64 lane][16 B]   : 67108864 (262144)
//   WXF  bf16 frag-linear [8 kt][32 nb][64 lane][8]    : 67371008 (262144)
//   GP8  f32 [512][8]                                  : 67633152 (16384)
//   BVEC f32 [512]                                     : 67649536
//   WCV  f32 [512]                                     : 67651584
//   SCOL f32 [512]                                     : 67653632
//   WTS  f32 [256]                                     : 67657728
#define WS_W2I8 67108864
#define WS_WXF  67371008
#define WS_GP8  67633152
#define WS_BVEC 67649536
#define WS_WCV  67651584
#define WS_SCOL 67653632
#define WS_WTS  67657728

// blocks 0-31: Wh column-scales + i8 quant (frag-linear W2), coalesced reads.
// blocks 32-39: Wx -> WxF bf16 frag-linear via LDS transpose.
// block 40: tiny per-element prep: weights=sigmoid(theta), gating consts, b, Wc.
__global__ __launch_bounds__(256) void prep_weights(
    const float* __restrict__ Wh, const float* __restrict__ Wx,
    const float* __restrict__ theta, const float* __restrict__ b,
    const float* __restrict__ c, const float* __restrict__ sigma,
    const float* __restrict__ q, const float* __restrict__ Wc,
    int* __restrict__ W2, ushort* __restrict__ WxF,
    float* __restrict__ scol, float* __restrict__ out_w,
    float* __restrict__ gp8, float* __restrict__ bvec,
    float* __restrict__ wcv, float* __restrict__ wts) {
  __shared__ float lds[16544];  // 66176 B; reused by both roles
  const int t = threadIdx.x;

  if (blockIdx.x < 32) {
    const int nb = blockIdx.x;
    // phase 1: column absmax over 16 cols, coalesced 64B runs
    const int cc = t & 15, rg = t >> 4;
    float m = 0.f;
#pragma unroll
    for (int s = 0; s < 32; ++s)
      m = fmaxf(m, fabsf(Wh[(rg + s * 16) * H_ + nb * 16 + cc]));
    lds[rg * 16 + cc] = m;
    __syncthreads();
    if (t < 16) {
      float mm = lds[t];
#pragma unroll
      for (int s = 1; s < 16; ++s) mm = fmaxf(mm, lds[s * 16 + t]);
      mm = fmaxf(mm, 1e-20f);
      scol[nb * 16 + t] = mm / (127.f * 127.f);
      lds[256 + t] = 127.f / mm;
    }
    __syncthreads();
    // phase 2: quantize, W2 layout identical to R7
    const int lane = t & 63, dw = t >> 6;
    const int n = nb * 16 + (lane & 15);
    const float iv = lds[256 + (lane & 15)];
#pragma unroll
    for (int kt = 0; kt < 8; ++kt) {
      int pk = 0;
#pragma unroll
      for (int jj = 0; jj < 4; ++jj) {
        const int k = kt * 64 + ((lane >> 4) << 4) + dw * 4 + jj;
        int qv = (int)rintf(Wh[k * H_ + n] * iv);
        qv = min(127, max(-127, qv));
        pk |= (qv & 255) << (8 * jj);
      }
      W2[((kt * 32 + nb) * 64 + lane) * 4 + dw] = pk;
    }
  } else if (blockIdx.x < 40) {
    const int kt = blockIdx.x - 32;
    // stage Wx rows [kt*32, kt*32+32) x 512 into LDS, row stride 517
#pragma unroll
    for (int it = 0; it < 16; ++it) {
      const int lin = (it * 256 + t) * 4;
      const float4 v = *(const float4*)(Wx + kt * 32 * H_ + lin);
      const int f = lin >> 9, n0 = lin & 511;
      lds[f * 517 + n0 + 0] = v.x;
      lds[f * 517 + n0 + 1] = v.y;
      lds[f * 517 + n0 + 2] = v.z;
      lds[f * 517 + n0 + 3] = v.w;
    }
    __syncthreads();
    // write frag-linear: o = (nb*64+lane)*8 + j, coalesced 16B/lane runs
#pragma unroll
    for (int it = 0; it < 8; ++it) {
      const int o = (it * 256 + t) * 8;
      const int lane = (o >> 3) & 63, nb = o >> 9;
      const int n = nb * 16 + (lane & 15), fb = (lane >> 4) << 3;
      ushort v[8];
#pragma unroll
      for (int j = 0; j < 8; ++j) v[j] = f2bf(lds[(fb + j) * 517 + n]);
      *(short8*)(WxF + kt * 16384 + o) = *(short8*)v;
    }
  } else {
    // ex prep_small: 256 threads handle 512 items (i = t, t+256)
#pragma unroll
    for (int r = 0; r < 2; ++r) {
      const int i = t + r * 256;
      if (i < F_) {
        float w = 1.f / (1.f + __expf(-theta[i]));
        out_w[i] = w;
        wts[i] = w;
      }
      float a[3], cc[3], qq[3];
#pragma unroll
      for (int k = 0; k < 3; ++k) {
        float s = sigma[i * 3 + k];
        cc[k] = c[i * 3 + k];
        a[k] = -LOG2E / (2.f * s * s + 1e-8f);
        qq[k] = q[i * 3 + k];
      }
      gp8[i * 8 + 0] = cc[0];
      gp8[i * 8 + 1] = cc[1];
      gp8[i * 8 + 2] = cc[2];
      gp8[i * 8 + 3] = a[0];
      gp8[i * 8 + 4] = a[1];
      gp8[i * 8 + 5] = a[2];
      gp8[i * 8 + 6] = __uint_as_float((unsigned)f2bf(qq[0]) |
                                       ((unsigned)f2bf(qq[1]) << 16));
      gp8[i * 8 + 7] = __uint_as_float((unsigned)f2bf(qq[2]));
      bvec[i] = b[i];
      wcv[i] = Wc[i];
    }
  }
}

// xw2 = bf16(x*wts) @ bf16(Wx), 2 timesteps per block for B-frag reuse.
// grid (tt2=64, bblk64=8), 256 thr.
__global__ __launch_bounds__(256, 2) void gemm1_kernel(
    const float* __restrict__ x, const float* __restrict__ wts,
    const ushort* __restrict__ WxF, ushort* __restrict__ xw2) {
  __shared__ ushort A2[2][64][256];  // 64KB, XOR-swizzled 16B chunks by row
  const int tid = threadIdx.x;
  const int lane = tid & 63, wg = tid >> 6;
  const int col16 = lane & 15, quad = lane >> 4;
  const int tt2 = blockIdx.x, bb = blockIdx.y;

  {  // stage A for both timesteps; wave reads contiguous 1KB rows
    const float4 wv = *(const float4*)(wts + lane * 4);
#pragma unroll
    for (int s = 0; s < 2; ++s) {
      const int t = tt2 + s * 64;
#pragma unroll
      for (int it = 0; it < 16; ++it) {
        const int row = it * 4 + wg;
        float4 xv = *(const float4*)(x + ((size_t)(bb * 64 + row) * T_ + t) * F_ + lane * 4);
        ushort4 o;
        o.x = f2bf(xv.x * wv.x);
        o.y = f2bf(xv.y * wv.y);
        o.z = f2bf(xv.z * wv.z);
        o.w = f2bf(xv.w * wv.w);
        const int ki = (lane * 4) ^ ((row & 7) << 3);  // 16B-chunk XOR swizzle
        *(ushort4*)&A2[s][row][ki] = o;
      }
    }
  }
  __syncthreads();

  const float4v zero = {0.f, 0.f, 0.f, 0.f};
  const int arow = wg * 16 + col16;
#pragma unroll
  for (int nn = 0; nn < 2; ++nn) {
    float4v acc0[16], acc1[16];
#pragma unroll
    for (int i = 0; i < 16; ++i) { acc0[i] = zero; acc1[i] = zero; }
#pragma unroll
    for (int kt = 0; kt < 8; ++kt) {
      short8 bfv[16];
#pragma unroll
      for (int nt = 0; nt < 16; ++nt)
        bfv[nt] = *(const short8*)(WxF + ((kt * 32 + nn * 16 + nt) * 64 + lane) * 8);
      const int ki = (kt * 32 + quad * 8) ^ ((arow & 7) << 3);
      short8 af0 = *(const short8*)&A2[0][arow][ki];
      short8 af1 = *(const short8*)&A2[1][arow][ki];
#pragma unroll
      for (int nt = 0; nt < 16; ++nt) {
        acc0[nt] = __builtin_amdgcn_mfma_f32_16x16x32_bf16(af0, bfv[nt], acc0[nt], 0, 0, 0);
        acc1[nt] = __builtin_amdgcn_mfma_f32_16x16x32_bf16(af1, bfv[nt], acc1[nt], 0, 0, 0);
      }
    }
    // store into scan4 layout for both timesteps
#pragma unroll
    for (int s = 0; s < 2; ++s) {
      const int t = tt2 + s * 64;
#pragma unroll
      for (int nt = 0; nt < 16; ++nt) {
        const float4v a = s ? acc1[nt] : acc0[nt];
        ushort2 lo, hi;
        lo.x = f2bf(a[0]);
        lo.y = f2bf(a[1]);
        hi.x = f2bf(a[2]);
        hi.y = f2bf(a[3]);
        const int bg0 = bb * 32 + wg * 8 + quad * 2;
        const size_t off0 =
            (((size_t)t * 256 + bg0) * 8 + nn * 4 + (nt >> 2)) * 128 +
            ((nt & 3) * 16 + col16) * 2;
        *(ushort2*)(xw2 + off0) = lo;
        *(ushort2*)(xw2 + off0 + 1024) = hi;  // bg0+1
      }
    }
  }
}

// scan4 (= R11, best measured): 256 WGs x 512 thr; WG owns 2 batch rows;
// wave owns 64 cols. 2-row h mirror (stride 576, conflict-free); nt-pair
// MFMA chains with pair-A bpermute spread hidden under pair-B; fma-form
// Gaussian; v_perm qb pack.
__global__ __launch_bounds__(512, 2) void scan4_kernel(
    const ushort* __restrict__ xw2, const int4i* __restrict__ W2,
    const float* __restrict__ gp8, const float* __restrict__ bvec,
    const float* __restrict__ wcv, const float* __restrict__ scol,
    const float* __restrict__ bc, float* __restrict__ out) {
  __shared__ __align__(16) char hb[2][1152];  // [buf][row*576 + k], rows 0..1
  __shared__ float red[8][2];
  const int tid = threadIdx.x;
  const int lane = tid & 63, w = tid >> 6;
  const int col16 = lane & 15, quad = lane >> 4;
  const int bg = blockIdx.x;

  for (int i = tid; i < 576; i += 512) ((int*)hb)[i] = 0;

  int4i bfr[8][4];
#pragma unroll
  for (int kt = 0; kt < 8; ++kt)
#pragma unroll
    for (int nt = 0; nt < 4; ++nt)
      bfr[kt][nt] = W2[(kt * 32 + w * 4 + nt) * 64 + lane];

  const int col = w * 64 + lane;
  const float bcol = bvec[col], scl = scol[col], wcl = wcv[col];
  float4v g0 = *(const float4v*)(gp8 + col * 8);
  float4v g1 = *(const float4v*)(gp8 + col * 8 + 4);
  const float c0v = g0[0], c1v = g0[1], c2v = g0[2];
  const float a0v = g0[3], a1v = g1[0], a2v = g1[1];
  unsigned p01 = __float_as_uint(g1[2]);
  const float q0v = bf2f(p01 & 0xffffu);
  const float q1v = bf2f(p01 >> 16);
  const float q2v = bf2f(__float_as_uint(g1[3]) & 0xffffu);
  // fma-form Gaussian: m = exp2(a*z^2 + b*z + d), b=-2ac, d=a*c^2
  const float b0v = -2.f * a0v * c0v, d0v = a0v * c0v * c0v;
  const float b1v = -2.f * a1v * c1v, d1v = a1v * c1v * c1v;
  const float b2v = -2.f * a2v * c2v, d2v = a2v * c2v * c2v;

  // write-back pack: even lane stores row0 (cols c,c+1), odd lane row1
  // (cols c-1,c). v_perm sel: 0-3 pick bytes of src1(p1), 4-7 of src0(pk).
  const unsigned wsel = (lane & 1) ? 0x0501u : 0x0004u;
  const int woff = col + ((lane & 1) ? 575 : 0);

  float hreg[2] = {0.f, 0.f};
  const int4i izero = {0, 0, 0, 0};
  int4i areg[8];
#pragma unroll
  for (int kt = 0; kt < 8; ++kt) areg[kt] = izero;  // lanes col16>=2 stay 0

  const ushort* xwb = xw2 + ((size_t)bg * 8 + w) * 128 + lane * 2;
  unsigned xv = *(const unsigned*)xwb;
  unsigned xn;
  __syncthreads();

#pragma clang loop unroll(disable)
  for (int t = 0; t < T_; ++t) {
    const int tn = (t + 1) & 127;
    xn = *(const unsigned*)(xwb + (size_t)tn * XW_T_STRIDE);

    if (col16 < 2) {
      const char* abase = hb[t & 1] + col16 * 576;
#pragma unroll
      for (int kt = 0; kt < 8; ++kt)
        areg[kt] = *(const int4i*)(abase + kt * 64 + (quad << 4));
    }

    // pair A: nt 0,1 chains
    int4i acc0 = izero, acc1 = izero;
#pragma unroll
    for (int kt = 0; kt < 8; ++kt) {
      acc0 = __builtin_amdgcn_mfma_i32_16x16x64_i8(areg[kt], bfr[kt][0], acc0, 0, 0, 0);
      acc1 = __builtin_amdgcn_mfma_i32_16x16x64_i8(areg[kt], bfr[kt][1], acc1, 0, 0, 0);
    }
    // early spread of pair A (DS pipe is free while pair B MFMAs run)
    int t0[2], t1[2];
#pragma unroll
    for (int rg = 0; rg < 2; ++rg) {
      t0[rg] = __shfl(acc0[rg], col16, 64);
      t1[rg] = __shfl(acc1[rg], col16, 64);
    }
    // pair B: nt 2,3 chains
    int4i acc2 = izero, acc3 = izero;
#pragma unroll
    for (int kt = 0; kt < 8; ++kt) {
      acc2 = __builtin_amdgcn_mfma_i32_16x16x64_i8(areg[kt], bfr[kt][2], acc2, 0, 0, 0);
      acc3 = __builtin_amdgcn_mfma_i32_16x16x64_i8(areg[kt], bfr[kt][3], acc3, 0, 0, 0);
    }
    int t2[2], t3[2];
#pragma unroll
    for (int rg = 0; rg < 2; ++rg) {
      t2[rg] = __shfl(acc2[rg], col16, 64);
      t3[rg] = __shfl(acc3[rg], col16, 64);
    }

    int accq[2];
#pragma unroll
    for (int rg = 0; rg < 2; ++rg) {
      int sA = (quad & 1) ? t1[rg] : t0[rg];
      int sB = (quad & 1) ? t3[rg] : t2[rg];
      accq[rg] = (quad & 2) ? sB : sA;
    }

    int qb[2];
#pragma unroll
    for (int rg = 0; rg < 2; ++rg) {
      float v = __uint_as_float(rg ? (xv & 0xffff0000u) : (xv << 16));
      float z = v + bcol + (float)accq[rg] * scl;
      float e = fexp2(v * (2.f * LOG2E));
      float nw = 1.f - 2.f * frcp(1.f + e);            // tanh(v)
      float zz = z * z;
      float m0 = fexp2(fmaf(a0v, zz, fmaf(b0v, z, d0v)));
      float m1 = fexp2(fmaf(a1v, zz, fmaf(b1v, z, d1v)));
      float m2 = fexp2(fmaf(a2v, zz, fmaf(b2v, z, d2v)));
      float num = m0 * q0v + m1 * q1v + m2 * q2v;
      float den = m0 + m1 + m2 + 1e-8f;
      float s = num * frcp(den);
      float gg = frcp(1.f + fexp2(-s * LOG2E));        // sigmoid(s)
      float h = hreg[rg] + gg * (nw - hreg[rg]);
      hreg[rg] = h;
      qb[rg] = (int)rintf(h * 127.f);
    }

    if (t < T_ - 1) {
      // pk byte0 = qb0.b0, byte1 = qb1.b0
      int pk = (int)__builtin_amdgcn_perm((unsigned)qb[1], (unsigned)qb[0], 0x0400u);
      unsigned p1 = (unsigned)__shfl_xor(pk, 1, 64);
      unsigned v16 = __builtin_amdgcn_perm((unsigned)pk, p1, wsel);
      *(ushort*)(hb[(t + 1) & 1] + woff) = (ushort)v16;
      __syncthreads();
    }
    xv = xn;
  }

  float part[2];
#pragma unroll
  for (int rg = 0; rg < 2; ++rg) {
    part[rg] = hreg[rg] * wcl;
#pragma unroll
    for (int m = 1; m < 64; m <<= 1) part[rg] += __shfl_xor(part[rg], m, 64);
  }
  if (lane == 0) {
    red[w][0] = part[0];
    red[w][1] = part[1];
  }
  __syncthreads();
  if (tid < 2) {
    float s = bc[0];
#pragma unroll
    for (int ww = 0; ww < 8; ++ww) s += red[ww][tid];
    out[bg * 2 + tid] = s;
  }
}

extern "C" void kernel_launch(void* const* d_in, const int* in_sizes, int n_in,
                              void* d_out, int out_size, void* d_ws, size_t ws_size,
                              hipStream_t stream) {
  const float* x     = (const float*)d_in[0];
  const float* theta = (const float*)d_in[1];
  const float* Wx    = (const float*)d_in[2];
  const float* Wh    = (const float*)d_in[3];
  const float* b     = (const float*)d_in[4];
  const float* c     = (const float*)d_in[5];
  const float* sigma = (const float*)d_in[6];
  const float* q     = (const float*)d_in[7];
  const float* Wc    = (const float*)d_in[8];
  const float* bc    = (const float*)d_in[9];
  float* out = (float*)d_out;

  ushort* xw2 = (ushort*)d_ws;
  int*    W2  = (int*)((char*)d_ws + WS_W2I8);
  ushort* WxF = (ushort*)((char*)d_ws + WS_WXF);
  float*  gp8 = (float*)((char*)d_ws + WS_GP8);
  float*  bv  = (float*)((char*)d_ws + WS_BVEC);
  float*  wcv = (float*)((char*)d_ws + WS_WCV);
  float*  scl = (float*)((char*)d_ws + WS_SCOL);
  float*  wts = (float*)((char*)d_ws + WS_WTS);

  hipLaunchKernelGGL(prep_weights, dim3(41), dim3(256), 0, stream,
                     Wh, Wx, theta, b, c, sigma, q, Wc,
                     W2, WxF, scl, out + B_, gp8, bv, wcv, wts);
  hipLaunchKernelGGL(gemm1_kernel, dim3(64, 8), dim3(256), 0, stream,
                     x, wts, WxF, xw2);
  hipLaunchKernelGGL(scan4_kernel, dim3(256), dim3(512), 0, stream,
                     xw2, (const int4i*)W2, gp8, bv, wcv, scl, bc, out);
}